// Round 1
// baseline (1980.831 us; speedup 1.0000x reference)
//
#include <hip/hip_runtime.h>
#include <math.h>

#define NB 96
#define NA 48
#define NF 128
#define NK 64
#define NL 6
#define NN (NB*NA)     // 4608 nodes
#define F3 (3*NF)      // 384
#define CUTF 5.0f
// gamma = 1/((5/64)^2 + 1e-9), computed in double at compile time to match numpy
#define GAMMA_F ((float)(1.0 / (0.006103515625 + 1e-9)))
#define PI_F 3.14159265358979323846f

__device__ __forceinline__ float silu_f(float x) {
    return x / (1.0f + expf(-x));
}

// ---------------- init: s = emb[node_atom], v = 0 ----------------
__global__ void init_kernel(const float* __restrict__ emb, const int* __restrict__ node_atom,
                            float* __restrict__ s, float* __restrict__ v) {
    int n = blockIdx.x, f = threadIdx.x;
    int a = node_atom[n];
    s[n*NF + f] = emb[a*NF + f];
    v[n*F3 + f] = 0.f;
    v[n*F3 + NF + f] = 0.f;
    v[n*F3 + 2*NF + f] = 0.f;
}

// ---------------- phi = silu(s@w1+b1)@w2+b2  [per node, 16 nodes/block] ----------------
__global__ void phi_kernel(const float* __restrict__ s,
                           const float* __restrict__ w1, const float* __restrict__ b1,
                           const float* __restrict__ w2, const float* __restrict__ b2,
                           float* __restrict__ phi) {
    __shared__ float st[16][NF];
    __shared__ float ht[16][NF];
    int f = threadIdx.x;
    int n0 = blockIdx.x * 16;
    #pragma unroll
    for (int n = 0; n < 16; ++n) st[n][f] = s[(n0+n)*NF + f];
    __syncthreads();
    float bb = b1[f];
    float acc[16];
    #pragma unroll
    for (int n = 0; n < 16; ++n) acc[n] = bb;
    for (int g = 0; g < NF; ++g) {
        float w = w1[g*NF + f];
        #pragma unroll
        for (int n = 0; n < 16; ++n) acc[n] = fmaf(st[n][g], w, acc[n]);
    }
    #pragma unroll
    for (int n = 0; n < 16; ++n) ht[n][f] = silu_f(acc[n]);
    __syncthreads();
    float b20 = b2[f], b21 = b2[NF+f], b22 = b2[2*NF+f];
    float a0[16], a1[16], a2[16];
    #pragma unroll
    for (int n = 0; n < 16; ++n) { a0[n]=b20; a1[n]=b21; a2[n]=b22; }
    for (int g = 0; g < NF; ++g) {
        float w0 = w2[g*F3 + f];
        float wA = w2[g*F3 + NF + f];
        float wB = w2[g*F3 + 2*NF + f];
        #pragma unroll
        for (int n = 0; n < 16; ++n) {
            float hv = ht[n][g];
            a0[n] = fmaf(hv, w0, a0[n]);
            a1[n] = fmaf(hv, wA, a1[n]);
            a2[n] = fmaf(hv, wB, a2[n]);
        }
    }
    #pragma unroll
    for (int n = 0; n < 16; ++n) {
        phi[(n0+n)*F3 + f]        = a0[n];
        phi[(n0+n)*F3 + NF + f]   = a1[n];
        phi[(n0+n)*F3 + 2*NF + f] = a2[n];
    }
}

// ---------------- message: per target atom i, sum over neighbors j ----------------
// 384 threads: t = output feature in [0,384). grp = t>>7 (wave-uniform: 128 = 2 waves)
//   grp0 -> ds (scalar residual), grp1 -> dvv*v_j, grp2 -> dvs*dir
__global__ void __launch_bounds__(384) message_kernel(
        const float* __restrict__ pos, const float* __restrict__ sIn,
        const float* __restrict__ vIn, const float* __restrict__ phi,
        const float* __restrict__ rbf_w, const float* __restrict__ rbf_b,
        float* __restrict__ sOut, float* __restrict__ vOut) {
    int i = blockIdx.x;
    int b = i / NA, il = i % NA;
    int t = threadIdx.x;
    int grp = t >> 7, f = t & (NF-1);
    __shared__ float px[NA], py[NA], pz[NA];
    __shared__ __align__(16) float tk[NA][NK];   // rbf * w_env
    __shared__ float wenvS[NA];
    __shared__ float dirS[NA][3];
    __shared__ float red[3][NF];
    if (t < NA) {
        px[t] = pos[(b*NA+t)*3 + 0];
        py[t] = pos[(b*NA+t)*3 + 1];
        pz[t] = pos[(b*NA+t)*3 + 2];
    }
    __syncthreads();
    float pix = px[il], piy = py[il], piz = pz[il];
    {
        int j = t >> 3;           // 48 neighbors, 8 threads each
        int klo = (t & 7) * 8;    // 8 rbf bins per thread
        float dx = pix - px[j], dy = piy - py[j], dz = piz - pz[j];
        float d2 = dx*dx + dy*dy + dz*dz;
        float dd = sqrtf((j == il) ? 1.0f : d2);   // matches where(eye,1,d2)
        bool valid = (j != il) && (dd < CUTF);
        float we = valid ? 0.5f*(cosf(PI_F * dd / CUTF) + 1.0f) : 0.0f;
        if ((t & 7) == 0) {
            wenvS[j] = we;
            float inv = 1.0f / dd;
            dirS[j][0] = dx*inv; dirS[j][1] = dy*inv; dirS[j][2] = dz*inv;
        }
        #pragma unroll
        for (int kk = 0; kk < 8; ++kk) {
            int k = klo + kk;
            float c = CUTF * (float)k / 63.0f;
            float df = dd - c;
            tk[j][k] = expf(-GAMMA_F * df * df) * we;
        }
    }
    // rbf_w column for this output feature lives in registers across the j-loop
    float wcol[NK];
    #pragma unroll
    for (int k = 0; k < NK; ++k) wcol[k] = rbf_w[k*F3 + t];
    float rb = rbf_b[t];
    __syncthreads();
    float accS = 0.f, av0 = 0.f, av1 = 0.f, av2 = 0.f;
    for (int j = 0; j < NA; ++j) {
        float we = wenvS[j];
        if (we == 0.f) continue;          // block-uniform skip (masked / diagonal)
        const float4* t4 = (const float4*)(&tk[j][0]);
        float acc = 0.f;
        #pragma unroll
        for (int k4 = 0; k4 < NK/4; ++k4) {
            float4 tv = t4[k4];
            acc = fmaf(tv.x, wcol[4*k4+0], acc);
            acc = fmaf(tv.y, wcol[4*k4+1], acc);
            acc = fmaf(tv.z, wcol[4*k4+2], acc);
            acc = fmaf(tv.w, wcol[4*k4+3], acc);
        }
        float Wf = fmaf(rb, we, acc);     // (rbf@rbf_w + rbf_b) * w_env
        int gj = b*NA + j;
        float x = phi[gj*F3 + t] * Wf;    // phi of sender j
        if (grp == 0) {
            accS += x;
        } else if (grp == 1) {
            av0 = fmaf(x, vIn[gj*F3 + f],        av0);
            av1 = fmaf(x, vIn[gj*F3 + NF + f],   av1);
            av2 = fmaf(x, vIn[gj*F3 + 2*NF + f], av2);
        } else {
            av0 = fmaf(x, dirS[j][0], av0);
            av1 = fmaf(x, dirS[j][1], av1);
            av2 = fmaf(x, dirS[j][2], av2);
        }
    }
    if (grp == 2) { red[0][f] = av0; red[1][f] = av1; red[2][f] = av2; }
    __syncthreads();
    if (grp == 0) {
        sOut[i*NF + f] = sIn[i*NF + f] + accS;
    } else if (grp == 1) {
        vOut[i*F3 + f]        = vIn[i*F3 + f]        + av0 + red[0][f];
        vOut[i*F3 + NF + f]   = vIn[i*F3 + NF + f]   + av1 + red[1][f];
        vOut[i*F3 + 2*NF + f] = vIn[i*F3 + 2*NF + f] + av2 + red[2][f];
    }
}

// ---------------- update block: gated equivariant update, 4 nodes/block, in-place ----------------
__global__ void update_kernel(const float* __restrict__ U, const float* __restrict__ V,
                              const float* __restrict__ w1, const float* __restrict__ b1,
                              const float* __restrict__ w2, const float* __restrict__ b2,
                              float* __restrict__ s, float* __restrict__ v) {
    __shared__ float st[4][NF];
    __shared__ float vt[4][3][NF];
    __shared__ float vn[4][NF];
    __shared__ float ht[4][NF];
    int f = threadIdx.x;
    int n0 = blockIdx.x * 4;
    #pragma unroll
    for (int n = 0; n < 4; ++n) {
        st[n][f]    = s[(n0+n)*NF + f];
        vt[n][0][f] = v[(n0+n)*F3 + f];
        vt[n][1][f] = v[(n0+n)*F3 + NF + f];
        vt[n][2][f] = v[(n0+n)*F3 + 2*NF + f];
    }
    __syncthreads();
    float uv[4][3] = {}, vv[4][3] = {};
    for (int g = 0; g < NF; ++g) {
        float uw = U[g*NF + f];
        float vw = V[g*NF + f];
        #pragma unroll
        for (int n = 0; n < 4; ++n) {
            float v0 = vt[n][0][g], v1 = vt[n][1][g], v2 = vt[n][2][g];
            uv[n][0] = fmaf(v0, uw, uv[n][0]);
            uv[n][1] = fmaf(v1, uw, uv[n][1]);
            uv[n][2] = fmaf(v2, uw, uv[n][2]);
            vv[n][0] = fmaf(v0, vw, vv[n][0]);
            vv[n][1] = fmaf(v1, vw, vv[n][1]);
            vv[n][2] = fmaf(v2, vw, vv[n][2]);
        }
    }
    #pragma unroll
    for (int n = 0; n < 4; ++n)
        vn[n][f] = sqrtf(vv[n][0]*vv[n][0] + vv[n][1]*vv[n][1] + vv[n][2]*vv[n][2] + 1e-8f);
    __syncthreads();
    float bb = b1[f];
    float hacc[4] = {bb, bb, bb, bb};
    for (int g = 0; g < NF; ++g) {
        float w = w1[g*NF + f];
        #pragma unroll
        for (int n = 0; n < 4; ++n) hacc[n] = fmaf(st[n][g], w, hacc[n]);
    }
    for (int g = 0; g < NF; ++g) {
        float w = w1[(NF+g)*NF + f];
        #pragma unroll
        for (int n = 0; n < 4; ++n) hacc[n] = fmaf(vn[n][g], w, hacc[n]);
    }
    #pragma unroll
    for (int n = 0; n < 4; ++n) ht[n][f] = silu_f(hacc[n]);
    __syncthreads();
    float b20 = b2[f], b21 = b2[NF+f], b22 = b2[2*NF+f];
    float a0[4], a1[4], a2[4];
    #pragma unroll
    for (int n = 0; n < 4; ++n) { a0[n]=b20; a1[n]=b21; a2[n]=b22; }
    for (int g = 0; g < NF; ++g) {
        float w0 = w2[g*F3 + f], wA = w2[g*F3 + NF + f], wB = w2[g*F3 + 2*NF + f];
        #pragma unroll
        for (int n = 0; n < 4; ++n) {
            float hv = ht[n][g];
            a0[n] = fmaf(hv, w0, a0[n]);
            a1[n] = fmaf(hv, wA, a1[n]);
            a2[n] = fmaf(hv, wB, a2[n]);
        }
    }
    #pragma unroll
    for (int n = 0; n < 4; ++n) {
        float dot = uv[n][0]*vv[n][0] + uv[n][1]*vv[n][1] + uv[n][2]*vv[n][2];
        s[(n0+n)*NF + f] = st[n][f] + a1[n]*dot + a2[n];
        v[(n0+n)*F3 + f]        = vt[n][0][f] + a0[n]*uv[n][0];
        v[(n0+n)*F3 + NF + f]   = vt[n][1][f] + a0[n]*uv[n][1];
        v[(n0+n)*F3 + 2*NF + f] = vt[n][2][f] + a0[n]*uv[n][2];
    }
}

// ---------------- output head ----------------
__global__ void zero_out_kernel(float* __restrict__ out) {
    out[threadIdx.x] = 0.f;
}

__global__ void out_kernel(const float* __restrict__ s,
                           const float* __restrict__ w1, const float* __restrict__ b1,
                           const float* __restrict__ w2, const float* __restrict__ b2,
                           float* __restrict__ out) {
    int n = blockIdx.x;
    int f = threadIdx.x;
    __shared__ float sh[NF];
    __shared__ float r2[2];
    sh[f] = s[n*NF + f];
    __syncthreads();
    float acc = b1[f];
    for (int g = 0; g < NF; ++g) acc = fmaf(sh[g], w1[g*NF + f], acc);
    float p = silu_f(acc) * w2[f];
    #pragma unroll
    for (int off = 32; off > 0; off >>= 1) p += __shfl_down(p, off, 64);
    if ((f & 63) == 0) r2[f >> 6] = p;
    __syncthreads();
    if (f == 0) atomicAdd(&out[n / NA], r2[0] + r2[1] + b2[0]);
}

extern "C" void kernel_launch(void* const* d_in, const int* in_sizes, int n_in,
                              void* d_out, int out_size, void* d_ws, size_t ws_size,
                              hipStream_t stream) {
    (void)in_sizes; (void)n_in; (void)out_size; (void)ws_size;
    const float* pos      = (const float*)d_in[1];
    const int*   node_atom= (const int*)  d_in[3];
    const float* emb      = (const float*)d_in[4];
    const float* msg_w1   = (const float*)d_in[5];
    const float* msg_b1   = (const float*)d_in[6];
    const float* msg_w2   = (const float*)d_in[7];
    const float* msg_b2   = (const float*)d_in[8];
    const float* rbf_w    = (const float*)d_in[9];
    const float* rbf_b    = (const float*)d_in[10];
    const float* upd_U    = (const float*)d_in[11];
    const float* upd_V    = (const float*)d_in[12];
    const float* upd_w1   = (const float*)d_in[13];
    const float* upd_b1   = (const float*)d_in[14];
    const float* upd_w2   = (const float*)d_in[15];
    const float* upd_b2   = (const float*)d_in[16];
    const float* out_w1   = (const float*)d_in[17];
    const float* out_b1   = (const float*)d_in[18];
    const float* out_w2   = (const float*)d_in[19];
    const float* out_b2   = (const float*)d_in[20];
    float* out = (float*)d_out;

    float* ws  = (float*)d_ws;
    float* sA  = ws; ws += (size_t)NN*NF;
    float* sB  = ws; ws += (size_t)NN*NF;
    float* vA  = ws; ws += (size_t)NN*F3;
    float* vB  = ws; ws += (size_t)NN*F3;
    float* phi = ws; ws += (size_t)NN*F3;

    init_kernel<<<NN, NF, 0, stream>>>(emb, node_atom, sA, vA);
    float* sC = sA; float* vC = vA; float* sN = sB; float* vN = vB;
    for (int l = 0; l < NL; ++l) {
        phi_kernel<<<NN/16, NF, 0, stream>>>(sC, msg_w1 + (size_t)l*NF*NF, msg_b1 + (size_t)l*NF,
                                             msg_w2 + (size_t)l*NF*F3, msg_b2 + (size_t)l*F3, phi);
        message_kernel<<<NN, F3, 0, stream>>>(pos, sC, vC, phi,
                                              rbf_w + (size_t)l*NK*F3, rbf_b + (size_t)l*F3, sN, vN);
        update_kernel<<<NN/4, NF, 0, stream>>>(upd_U + (size_t)l*NF*NF, upd_V + (size_t)l*NF*NF,
                                               upd_w1 + (size_t)l*2*NF*NF, upd_b1 + (size_t)l*NF,
                                               upd_w2 + (size_t)l*NF*F3, upd_b2 + (size_t)l*F3, sN, vN);
        float* t;
        t = sC; sC = sN; sN = t;
        t = vC; vC = vN; vN = t;
    }
    zero_out_kernel<<<1, NB, 0, stream>>>(out);
    out_kernel<<<NN, NF, 0, stream>>>(sC, out_w1, out_b1, out_w2, out_b2, out);
}

// Round 2
// 1328.115 us; speedup vs baseline: 1.4915x; 1.4915x over previous
//
#include <hip/hip_runtime.h>
#include <math.h>

#define NB 96
#define NA 48
#define NF 128
#define NK 64
#define NL 6
#define NN (NB*NA)     // 4608 nodes
#define F3 (3*NF)      // 384
#define CUTF 5.0f
#define GAMMA_F ((float)(1.0 / (0.006103515625 + 1e-9)))
#define PI_F 3.14159265358979323846f
#define LDA 72         // tk LDS row stride in shorts: 144 B (16B-aligned, bank stagger 4)

typedef __attribute__((ext_vector_type(8))) short short8;
typedef __attribute__((ext_vector_type(4))) float floatx4;

__device__ __forceinline__ float silu_f(float x) { return x / (1.0f + expf(-x)); }

__device__ __forceinline__ short f2bf(float x) {
    unsigned u = __builtin_bit_cast(unsigned, x);
    unsigned r = (u + 0x7fffu + ((u >> 16) & 1u)) >> 16;   // RNE
    return (short)r;
}
__device__ __forceinline__ float bf2f(short h) {
    unsigned u = ((unsigned)(unsigned short)h) << 16;
    return __builtin_bit_cast(float, u);
}

// ---------------- prep: rbf_w [L][K][3F] -> transposed bf16 hi/lo [L][3F][K] ----------------
__global__ void prep_rbfw_kernel(const float* __restrict__ rbf_w,
                                 short* __restrict__ btHi, short* __restrict__ btLo) {
    int l = blockIdx.x / F3, t = blockIdx.x % F3;
    int k = threadIdx.x;
    float w = rbf_w[((size_t)l*NK + k)*F3 + t];
    short h = f2bf(w);
    btHi[((size_t)l*F3 + t)*NK + k] = h;
    btLo[((size_t)l*F3 + t)*NK + k] = f2bf(w - bf2f(h));
}

// ---------------- init: s = emb[node_atom], v = 0 ----------------
__global__ void init_kernel(const float* __restrict__ emb, const int* __restrict__ node_atom,
                            float* __restrict__ s, float* __restrict__ v) {
    int n = blockIdx.x, f = threadIdx.x;
    int a = node_atom[n];
    s[n*NF + f] = emb[a*NF + f];
    v[n*F3 + f] = 0.f;
    v[n*F3 + NF + f] = 0.f;
    v[n*F3 + 2*NF + f] = 0.f;
}

// ---------------- phi = silu(s@w1+b1)@w2+b2  [4 nodes/block] ----------------
__global__ void phi_kernel(const float* __restrict__ s,
                           const float* __restrict__ w1, const float* __restrict__ b1,
                           const float* __restrict__ w2, const float* __restrict__ b2,
                           float* __restrict__ phi) {
    __shared__ float st[4][NF];
    __shared__ float ht[4][NF];
    int f = threadIdx.x;
    int n0 = blockIdx.x * 4;
    #pragma unroll
    for (int n = 0; n < 4; ++n) st[n][f] = s[(n0+n)*NF + f];
    __syncthreads();
    float bb = b1[f];
    float acc[4] = {bb, bb, bb, bb};
    for (int g = 0; g < NF; ++g) {
        float w = w1[g*NF + f];
        #pragma unroll
        for (int n = 0; n < 4; ++n) acc[n] = fmaf(st[n][g], w, acc[n]);
    }
    #pragma unroll
    for (int n = 0; n < 4; ++n) ht[n][f] = silu_f(acc[n]);
    __syncthreads();
    float b20 = b2[f], b21 = b2[NF+f], b22 = b2[2*NF+f];
    float a0[4], a1[4], a2[4];
    #pragma unroll
    for (int n = 0; n < 4; ++n) { a0[n]=b20; a1[n]=b21; a2[n]=b22; }
    for (int g = 0; g < NF; ++g) {
        float w0 = w2[g*F3 + f];
        float wA = w2[g*F3 + NF + f];
        float wB = w2[g*F3 + 2*NF + f];
        #pragma unroll
        for (int n = 0; n < 4; ++n) {
            float hv = ht[n][g];
            a0[n] = fmaf(hv, w0, a0[n]);
            a1[n] = fmaf(hv, wA, a1[n]);
            a2[n] = fmaf(hv, wB, a2[n]);
        }
    }
    #pragma unroll
    for (int n = 0; n < 4; ++n) {
        phi[(n0+n)*F3 + f]        = a0[n];
        phi[(n0+n)*F3 + NF + f]   = a1[n];
        phi[(n0+n)*F3 + 2*NF + f] = a2[n];
    }
}

// ---------------- message: MFMA bf16x3 RBF projection + fragment-space combine ----------------
// Block = target atom i, 384 threads = 6 waves. Wave w owns t-chunk [64w, 64w+64):
//   waves 0-1 -> ds, waves 2-3 -> dvv, waves 4-5 -> dvs (feature-group aligned).
// Invalid/diagonal pairs: tk row == 0 and w_env == 0 -> contribute exactly 0 (no masking).
__global__ void __launch_bounds__(384) message_kernel(
        const float* __restrict__ pos, const float* __restrict__ sIn,
        const float* __restrict__ vIn, const float* __restrict__ phi,
        const short* __restrict__ btHi_l, const short* __restrict__ btLo_l,
        const float* __restrict__ rbf_b_l,
        float* __restrict__ sOut, float* __restrict__ vOut) {
    int i = blockIdx.x;
    int b = i / NA;
    int t = threadIdx.x;
    int w = t >> 6;
    int lane = t & 63;
    int quad = lane >> 4, col = lane & 15;

    __shared__ float px[NA], py[NA], pz[NA];
    __shared__ __align__(16) short tkHi[NA][LDA];
    __shared__ __align__(16) short tkLo[NA][LDA];
    __shared__ float wenvS[NA];
    __shared__ float dirS[NA][3];
    __shared__ float red[3][NF];

    if (t < NA) {
        px[t] = pos[(b*NA+t)*3 + 0];
        py[t] = pos[(b*NA+t)*3 + 1];
        pz[t] = pos[(b*NA+t)*3 + 2];
    }
    __syncthreads();
    {   // stage 1: geometry + rbf*w_env, split to bf16 hi/lo. 8 threads per neighbor j.
        int il = i % NA;
        int j = t >> 3;
        int klo = (t & 7) * 8;
        float dx = px[il] - px[j], dy = py[il] - py[j], dz = pz[il] - pz[j];
        float d2 = dx*dx + dy*dy + dz*dz;
        float dd = sqrtf((j == il) ? 1.0f : d2);          // matches where(eye,1,d2)
        bool valid = (j != il) && (dd < CUTF);
        float we = valid ? 0.5f*(cosf(PI_F * dd / CUTF) + 1.0f) : 0.0f;
        if ((t & 7) == 0) {
            wenvS[j] = we;
            float inv = 1.0f / dd;
            dirS[j][0] = dx*inv; dirS[j][1] = dy*inv; dirS[j][2] = dz*inv;
        }
        short8 h8, l8;
        #pragma unroll
        for (int kk = 0; kk < 8; ++kk) {
            int k = klo + kk;
            float c = CUTF * (float)k / 63.0f;
            float df = dd - c;
            float val = expf(-GAMMA_F * df * df) * we;
            short h = f2bf(val);
            h8[kk] = h;
            l8[kk] = f2bf(val - bf2f(h));
        }
        *(short8*)(&tkHi[j][klo]) = h8;
        *(short8*)(&tkLo[j][klo]) = l8;
    }

    // B fragments (rbf_w^T hi/lo) from global — L1/L2-resident, reused by all blocks
    short8 BH[4][2], BL[4][2];
    #pragma unroll
    for (int nt = 0; nt < 4; ++nt) {
        int trow = w*64 + nt*16 + col;
        #pragma unroll
        for (int ks = 0; ks < 2; ++ks) {
            int off = trow*NK + ks*32 + quad*8;
            BH[nt][ks] = *(const short8*)(btHi_l + off);
            BL[nt][ks] = *(const short8*)(btLo_l + off);
        }
    }
    float rb[4];
    #pragma unroll
    for (int nt = 0; nt < 4; ++nt) rb[nt] = rbf_b_l[w*64 + nt*16 + col];

    __syncthreads();

    // MFMA: C[j, t] = tk[48x64] @ rbf_wT[t-chunk][64]^T, bf16x3 (hi*hi + lo*hi + hi*lo)
    floatx4 C[3][4];
    #pragma unroll
    for (int mt = 0; mt < 3; ++mt)
        #pragma unroll
        for (int nt = 0; nt < 4; ++nt) C[mt][nt] = (floatx4){0.f,0.f,0.f,0.f};
    #pragma unroll
    for (int mt = 0; mt < 3; ++mt) {
        #pragma unroll
        for (int ks = 0; ks < 2; ++ks) {
            short8 ah = *(const short8*)(&tkHi[mt*16 + col][ks*32 + quad*8]);
            short8 al = *(const short8*)(&tkLo[mt*16 + col][ks*32 + quad*8]);
            #pragma unroll
            for (int nt = 0; nt < 4; ++nt) {
                C[mt][nt] = __builtin_amdgcn_mfma_f32_16x16x32_bf16(ah, BH[nt][ks], C[mt][nt], 0, 0, 0);
                C[mt][nt] = __builtin_amdgcn_mfma_f32_16x16x32_bf16(al, BH[nt][ks], C[mt][nt], 0, 0, 0);
                C[mt][nt] = __builtin_amdgcn_mfma_f32_16x16x32_bf16(ah, BL[nt][ks], C[mt][nt], 0, 0, 0);
            }
        }
    }

    // Combine directly from C fragments: lane holds (j = mt*16 + quad*4 + r, t = w*64 + nt*16 + col)
    int g = w >> 1;
    float a0[4] = {0.f,0.f,0.f,0.f}, a1[4] = {0.f,0.f,0.f,0.f}, a2[4] = {0.f,0.f,0.f,0.f};
    if (g == 0) {
        float acc[4] = {0.f,0.f,0.f,0.f};
        #pragma unroll
        for (int mt = 0; mt < 3; ++mt) {
            #pragma unroll
            for (int r = 0; r < 4; ++r) {
                int j = mt*16 + quad*4 + r;
                int gj = b*NA + j;
                float we = wenvS[j];
                const float* php = phi + (size_t)gj*F3 + w*64 + col;
                #pragma unroll
                for (int nt = 0; nt < 4; ++nt) {
                    float Wf = fmaf(rb[nt], we, C[mt][nt][r]);
                    acc[nt] = fmaf(php[nt*16], Wf, acc[nt]);
                }
            }
        }
        #pragma unroll
        for (int nt = 0; nt < 4; ++nt) {
            acc[nt] += __shfl_xor(acc[nt], 16, 64);
            acc[nt] += __shfl_xor(acc[nt], 32, 64);
        }
        if (quad == 0) {
            #pragma unroll
            for (int nt = 0; nt < 4; ++nt) {
                int tg = w*64 + nt*16 + col;
                sOut[(size_t)i*NF + tg] = sIn[(size_t)i*NF + tg] + acc[nt];
            }
        }
    } else if (g == 1) {          // dvv: sum_j x * v_j[c][f],  f = (w-2)*64 + nt*16 + col
        #pragma unroll
        for (int mt = 0; mt < 3; ++mt) {
            #pragma unroll
            for (int r = 0; r < 4; ++r) {
                int j = mt*16 + quad*4 + r;
                int gj = b*NA + j;
                float we = wenvS[j];
                const float* php = phi + (size_t)gj*F3 + NF + (w-2)*64 + col;
                const float* vp  = vIn + (size_t)gj*F3 + (w-2)*64 + col;
                #pragma unroll
                for (int nt = 0; nt < 4; ++nt) {
                    float Wf = fmaf(rb[nt], we, C[mt][nt][r]);
                    float x = php[nt*16] * Wf;
                    a0[nt] = fmaf(x, vp[nt*16],        a0[nt]);
                    a1[nt] = fmaf(x, vp[NF + nt*16],   a1[nt]);
                    a2[nt] = fmaf(x, vp[2*NF + nt*16], a2[nt]);
                }
            }
        }
        #pragma unroll
        for (int nt = 0; nt < 4; ++nt) {
            a0[nt] += __shfl_xor(a0[nt], 16, 64); a0[nt] += __shfl_xor(a0[nt], 32, 64);
            a1[nt] += __shfl_xor(a1[nt], 16, 64); a1[nt] += __shfl_xor(a1[nt], 32, 64);
            a2[nt] += __shfl_xor(a2[nt], 16, 64); a2[nt] += __shfl_xor(a2[nt], 32, 64);
        }
    } else {                      // dvs: sum_j x * dir[j][c],  f = (w-4)*64 + nt*16 + col
        #pragma unroll
        for (int mt = 0; mt < 3; ++mt) {
            #pragma unroll
            for (int r = 0; r < 4; ++r) {
                int j = mt*16 + quad*4 + r;
                int gj = b*NA + j;
                float we = wenvS[j];
                float d0 = dirS[j][0], d1 = dirS[j][1], d2v = dirS[j][2];
                const float* php = phi + (size_t)gj*F3 + 2*NF + (w-4)*64 + col;
                #pragma unroll
                for (int nt = 0; nt < 4; ++nt) {
                    float Wf = fmaf(rb[nt], we, C[mt][nt][r]);
                    float x = php[nt*16] * Wf;
                    a0[nt] = fmaf(x, d0,  a0[nt]);
                    a1[nt] = fmaf(x, d1,  a1[nt]);
                    a2[nt] = fmaf(x, d2v, a2[nt]);
                }
            }
        }
        #pragma unroll
        for (int nt = 0; nt < 4; ++nt) {
            a0[nt] += __shfl_xor(a0[nt], 16, 64); a0[nt] += __shfl_xor(a0[nt], 32, 64);
            a1[nt] += __shfl_xor(a1[nt], 16, 64); a1[nt] += __shfl_xor(a1[nt], 32, 64);
            a2[nt] += __shfl_xor(a2[nt], 16, 64); a2[nt] += __shfl_xor(a2[nt], 32, 64);
        }
        if (quad == 0) {
            #pragma unroll
            for (int nt = 0; nt < 4; ++nt) {
                int f = (w-4)*64 + nt*16 + col;
                red[0][f] = a0[nt]; red[1][f] = a1[nt]; red[2][f] = a2[nt];
            }
        }
    }
    __syncthreads();
    if (g == 1 && quad == 0) {
        #pragma unroll
        for (int nt = 0; nt < 4; ++nt) {
            int f = (w-2)*64 + nt*16 + col;
            vOut[(size_t)i*F3 + f]        = vIn[(size_t)i*F3 + f]        + a0[nt] + red[0][f];
            vOut[(size_t)i*F3 + NF + f]   = vIn[(size_t)i*F3 + NF + f]   + a1[nt] + red[1][f];
            vOut[(size_t)i*F3 + 2*NF + f] = vIn[(size_t)i*F3 + 2*NF + f] + a2[nt] + red[2][f];
        }
    }
}

// ---------------- update block: gated equivariant update, 4 nodes/block, in-place ----------------
__global__ void update_kernel(const float* __restrict__ U, const float* __restrict__ V,
                              const float* __restrict__ w1, const float* __restrict__ b1,
                              const float* __restrict__ w2, const float* __restrict__ b2,
                              float* __restrict__ s, float* __restrict__ v) {
    __shared__ float st[4][NF];
    __shared__ float vt[4][3][NF];
    __shared__ float vn[4][NF];
    __shared__ float ht[4][NF];
    int f = threadIdx.x;
    int n0 = blockIdx.x * 4;
    #pragma unroll
    for (int n = 0; n < 4; ++n) {
        st[n][f]    = s[(n0+n)*NF + f];
        vt[n][0][f] = v[(n0+n)*F3 + f];
        vt[n][1][f] = v[(n0+n)*F3 + NF + f];
        vt[n][2][f] = v[(n0+n)*F3 + 2*NF + f];
    }
    __syncthreads();
    float uv[4][3] = {}, vv[4][3] = {};
    for (int g = 0; g < NF; ++g) {
        float uw = U[g*NF + f];
        float vw = V[g*NF + f];
        #pragma unroll
        for (int n = 0; n < 4; ++n) {
            float v0 = vt[n][0][g], v1 = vt[n][1][g], v2 = vt[n][2][g];
            uv[n][0] = fmaf(v0, uw, uv[n][0]);
            uv[n][1] = fmaf(v1, uw, uv[n][1]);
            uv[n][2] = fmaf(v2, uw, uv[n][2]);
            vv[n][0] = fmaf(v0, vw, vv[n][0]);
            vv[n][1] = fmaf(v1, vw, vv[n][1]);
            vv[n][2] = fmaf(v2, vw, vv[n][2]);
        }
    }
    #pragma unroll
    for (int n = 0; n < 4; ++n)
        vn[n][f] = sqrtf(vv[n][0]*vv[n][0] + vv[n][1]*vv[n][1] + vv[n][2]*vv[n][2] + 1e-8f);
    __syncthreads();
    float bb = b1[f];
    float hacc[4] = {bb, bb, bb, bb};
    for (int g = 0; g < NF; ++g) {
        float w = w1[g*NF + f];
        #pragma unroll
        for (int n = 0; n < 4; ++n) hacc[n] = fmaf(st[n][g], w, hacc[n]);
    }
    for (int g = 0; g < NF; ++g) {
        float w = w1[(NF+g)*NF + f];
        #pragma unroll
        for (int n = 0; n < 4; ++n) hacc[n] = fmaf(vn[n][g], w, hacc[n]);
    }
    #pragma unroll
    for (int n = 0; n < 4; ++n) ht[n][f] = silu_f(hacc[n]);
    __syncthreads();
    float b20 = b2[f], b21 = b2[NF+f], b22 = b2[2*NF+f];
    float a0[4], a1[4], a2[4];
    #pragma unroll
    for (int n = 0; n < 4; ++n) { a0[n]=b20; a1[n]=b21; a2[n]=b22; }
    for (int g = 0; g < NF; ++g) {
        float w0 = w2[g*F3 + f], wA = w2[g*F3 + NF + f], wB = w2[g*F3 + 2*NF + f];
        #pragma unroll
        for (int n = 0; n < 4; ++n) {
            float hv = ht[n][g];
            a0[n] = fmaf(hv, w0, a0[n]);
            a1[n] = fmaf(hv, wA, a1[n]);
            a2[n] = fmaf(hv, wB, a2[n]);
        }
    }
    #pragma unroll
    for (int n = 0; n < 4; ++n) {
        float dot = uv[n][0]*vv[n][0] + uv[n][1]*vv[n][1] + uv[n][2]*vv[n][2];
        s[(n0+n)*NF + f] = st[n][f] + a1[n]*dot + a2[n];
        v[(n0+n)*F3 + f]        = vt[n][0][f] + a0[n]*uv[n][0];
        v[(n0+n)*F3 + NF + f]   = vt[n][1][f] + a0[n]*uv[n][1];
        v[(n0+n)*F3 + 2*NF + f] = vt[n][2][f] + a0[n]*uv[n][2];
    }
}

// ---------------- output head ----------------
__global__ void zero_out_kernel(float* __restrict__ out) {
    out[threadIdx.x] = 0.f;
}

__global__ void out_kernel(const float* __restrict__ s,
                           const float* __restrict__ w1, const float* __restrict__ b1,
                           const float* __restrict__ w2, const float* __restrict__ b2,
                           float* __restrict__ out) {
    int n = blockIdx.x;
    int f = threadIdx.x;
    __shared__ float sh[NF];
    __shared__ float r2[2];
    sh[f] = s[n*NF + f];
    __syncthreads();
    float acc = b1[f];
    for (int g = 0; g < NF; ++g) acc = fmaf(sh[g], w1[g*NF + f], acc);
    float p = silu_f(acc) * w2[f];
    #pragma unroll
    for (int off = 32; off > 0; off >>= 1) p += __shfl_down(p, off, 64);
    if ((f & 63) == 0) r2[f >> 6] = p;
    __syncthreads();
    if (f == 0) atomicAdd(&out[n / NA], r2[0] + r2[1] + b2[0]);
}

extern "C" void kernel_launch(void* const* d_in, const int* in_sizes, int n_in,
                              void* d_out, int out_size, void* d_ws, size_t ws_size,
                              hipStream_t stream) {
    (void)in_sizes; (void)n_in; (void)out_size; (void)ws_size;
    const float* pos      = (const float*)d_in[1];
    const int*   node_atom= (const int*)  d_in[3];
    const float* emb      = (const float*)d_in[4];
    const float* msg_w1   = (const float*)d_in[5];
    const float* msg_b1   = (const float*)d_in[6];
    const float* msg_w2   = (const float*)d_in[7];
    const float* msg_b2   = (const float*)d_in[8];
    const float* rbf_w    = (const float*)d_in[9];
    const float* rbf_b    = (const float*)d_in[10];
    const float* upd_U    = (const float*)d_in[11];
    const float* upd_V    = (const float*)d_in[12];
    const float* upd_w1   = (const float*)d_in[13];
    const float* upd_b1   = (const float*)d_in[14];
    const float* upd_w2   = (const float*)d_in[15];
    const float* upd_b2   = (const float*)d_in[16];
    const float* out_w1   = (const float*)d_in[17];
    const float* out_b1   = (const float*)d_in[18];
    const float* out_w2   = (const float*)d_in[19];
    const float* out_b2   = (const float*)d_in[20];
    float* out = (float*)d_out;

    float* ws  = (float*)d_ws;
    float* sA  = ws; ws += (size_t)NN*NF;
    float* sB  = ws; ws += (size_t)NN*NF;
    float* vA  = ws; ws += (size_t)NN*F3;
    float* vB  = ws; ws += (size_t)NN*F3;
    float* phi = ws; ws += (size_t)NN*F3;
    short* btHi = (short*)ws;
    short* btLo = btHi + (size_t)NL*F3*NK;

    prep_rbfw_kernel<<<NL*F3, NK, 0, stream>>>(rbf_w, btHi, btLo);
    init_kernel<<<NN, NF, 0, stream>>>(emb, node_atom, sA, vA);
    float* sC = sA; float* vC = vA; float* sN = sB; float* vN = vB;
    for (int l = 0; l < NL; ++l) {
        phi_kernel<<<NN/4, NF, 0, stream>>>(sC, msg_w1 + (size_t)l*NF*NF, msg_b1 + (size_t)l*NF,
                                            msg_w2 + (size_t)l*NF*F3, msg_b2 + (size_t)l*F3, phi);
        message_kernel<<<NN, F3, 0, stream>>>(pos, sC, vC, phi,
                                              btHi + (size_t)l*F3*NK, btLo + (size_t)l*F3*NK,
                                              rbf_b + (size_t)l*F3, sN, vN);
        update_kernel<<<NN/4, NF, 0, stream>>>(upd_U + (size_t)l*NF*NF, upd_V + (size_t)l*NF*NF,
                                               upd_w1 + (size_t)l*2*NF*NF, upd_b1 + (size_t)l*NF,
                                               upd_w2 + (size_t)l*NF*F3, upd_b2 + (size_t)l*F3, sN, vN);
        float* t;
        t = sC; sC = sN; sN = t;
        t = vC; vC = vN; vN = t;
    }
    zero_out_kernel<<<1, NB, 0, stream>>>(out);
    out_kernel<<<NN, NF, 0, stream>>>(sC, out_w1, out_b1, out_w2, out_b2, out);
}